// Round 1
// baseline (2124.981 us; speedup 1.0000x reference)
//
#include <hip/hip_runtime.h>
#include <stdint.h>

#define T_TOKENS 8192
#define DDIM 2048
#define FDIM 4096
#define NEXP 8

typedef __attribute__((ext_vector_type(8))) short bf16x8;
typedef __attribute__((ext_vector_type(4))) float f32x4;

// round-to-nearest-even fp32 -> bf16 (finite inputs)
__device__ __forceinline__ unsigned short f2bf(float f) {
  unsigned int u = __float_as_uint(f);
  unsigned int r = (u + 0x7FFFu + ((u >> 16) & 1u)) >> 16;
  return (unsigned short)r;
}

__global__ void k_assign(const float* __restrict__ logits,
                         int* __restrict__ assign,
                         int* __restrict__ counts) {
  int t = blockIdx.x * blockDim.x + threadIdx.x;
  if (t >= T_TOKENS) return;
  const float* l = logits + (size_t)t * NEXP;
  float bv = l[0]; int be = 0;
#pragma unroll
  for (int e = 1; e < NEXP; ++e) {
    float v = l[e];
    if (v > bv) { bv = v; be = e; }   // strict > : first-max tiebreak like jnp.argmax
  }
  assign[t] = be;
  atomicAdd(&counts[be], 1);
}

__global__ void k_scan(const int* __restrict__ counts,
                       int* __restrict__ offsets) {
  if (threadIdx.x == 0) {
    int acc = 0;
    for (int e = 0; e < NEXP; ++e) { offsets[e] = acc; acc += counts[e]; }
  }
}

__global__ void k_place(const int* __restrict__ assign,
                        const int* __restrict__ offsets,
                        int* __restrict__ cursors,
                        int* __restrict__ perm) {
  int t = blockIdx.x * blockDim.x + threadIdx.x;
  if (t >= T_TOKENS) return;
  int e = assign[t];
  int pos = atomicAdd(&cursors[e], 1);
  perm[offsets[e] + pos] = t;
}

// gather tokens into bucket order, cast fp32 -> bf16
__global__ void k_gather_x(const float* __restrict__ x,
                           const int* __restrict__ perm,
                           unsigned short* __restrict__ xg) {
  int idx = blockIdx.x * blockDim.x + threadIdx.x;   // over T*D/4
  int slot = idx / (DDIM / 4);
  int c4 = idx - slot * (DDIM / 4);
  int tok = perm[slot];
  float4 v = ((const float4*)(x + (size_t)tok * DDIM))[c4];
  ushort4 o;
  o.x = f2bf(v.x); o.y = f2bf(v.y); o.z = f2bf(v.z); o.w = f2bf(v.w);
  ((ushort4*)(xg + (size_t)slot * DDIM))[c4] = o;
}

__global__ void k_cast(const float* __restrict__ src,
                       unsigned short* __restrict__ dst, int n4) {
  int i = blockIdx.x * blockDim.x + threadIdx.x;
  if (i >= n4) return;
  float4 v = ((const float4*)src)[i];
  ushort4 o;
  o.x = f2bf(v.x); o.y = f2bf(v.y); o.z = f2bf(v.z); o.w = f2bf(v.w);
  ((ushort4*)dst)[i] = o;
}

// Grouped GEMM, m97 structure: 128x128 tile, BK=32, global_load_lds width-16,
// mfma_f32_16x16x32_bf16, 4 waves each computing a 64x64 subtile (4x4 MFMA tiles).
// A is packed-by-bucket [T,K] bf16 (K-contiguous); Bw is [E,N,K] bf16 (K-contiguous,
// i.e. the natural w[e] layout = verified B^T GEMM).
// FIRST: epilogue = silu -> bf16 store to Hout.  !FIRST: fp32 scatter rows via perm.
template<bool FIRST>
__launch_bounds__(256)
__global__ void k_gemm(const unsigned short* __restrict__ Ap,
                       const unsigned short* __restrict__ Bw,
                       unsigned short* __restrict__ Hout,
                       float* __restrict__ Out,
                       const int* __restrict__ offsets,
                       const int* __restrict__ counts,
                       const int* __restrict__ perm) {
  constexpr int K = FIRST ? DDIM : FDIM;
  constexpr int N = FIRST ? FDIM : DDIM;
  const int e = blockIdx.z;
  const int Me = counts[e];
  const int rb = blockIdx.x * 128;
  if (rb >= Me) return;                       // early-exit padding blocks
  const int off = offsets[e];
  const int cb = blockIdx.y * 128;

  __shared__ unsigned short At[128 * 32];     // 8 KB, rows K-contiguous (64B/row)
  __shared__ unsigned short Bt[128 * 32];

  const int tid = threadIdx.x;
  const int wave = tid >> 6;
  const int lane = tid & 63;
  const int wr = (wave & 1) * 64;
  const int wc = (wave >> 1) * 64;

  // staging: 8KB tile = 8 chunks of 1KB (one wave-instruction each);
  // wave w handles chunks 2w, 2w+1. lane l -> row = chunk*16 + (l>>2), k-seg (l&3)*8.
  const int crow = lane >> 2;
  const int ckoff = (lane & 3) * 8;

  const unsigned short* gA[2];
  const unsigned short* gB[2];
#pragma unroll
  for (int c = 0; c < 2; ++c) {
    int row = wave * 32 + c * 16 + crow;
    int ar = rb + row; if (ar >= Me) ar = Me - 1;   // clamp ragged M (rows unused in epilogue)
    gA[c] = Ap + (size_t)(off + ar) * K + ckoff;
    gB[c] = Bw + (size_t)e * N * K + (size_t)(cb + row) * K + ckoff;
  }
  unsigned short* lA = &At[(size_t)(wave * 2) * 512];  // wave-uniform LDS base
  unsigned short* lB = &Bt[(size_t)(wave * 2) * 512];

  f32x4 acc[4][4] = {};

  for (int k0 = 0; k0 < K; k0 += 32) {
#pragma unroll
    for (int c = 0; c < 2; ++c) {
      __builtin_amdgcn_global_load_lds(
          (const __attribute__((address_space(1))) void*)(gA[c] + k0),
          (__attribute__((address_space(3))) void*)(lA + c * 512), 16, 0, 0);
      __builtin_amdgcn_global_load_lds(
          (const __attribute__((address_space(1))) void*)(gB[c] + k0),
          (__attribute__((address_space(3))) void*)(lB + c * 512), 16, 0, 0);
    }
    __syncthreads();

    bf16x8 af[4], bfr[4];
#pragma unroll
    for (int i = 0; i < 4; ++i) {
      // A-operand layout: m = lane&15, k = (lane>>4)*8 + j  -> contiguous 16B
      af[i]  = *(const bf16x8*)&At[(wr + i * 16 + (lane & 15)) * 32 + (lane >> 4) * 8];
      bfr[i] = *(const bf16x8*)&Bt[(wc + i * 16 + (lane & 15)) * 32 + (lane >> 4) * 8];
    }
#pragma unroll
    for (int i = 0; i < 4; ++i)
#pragma unroll
      for (int j = 0; j < 4; ++j)
        acc[i][j] = __builtin_amdgcn_mfma_f32_16x16x32_bf16(af[i], bfr[j], acc[i][j], 0, 0, 0);
    __syncthreads();
  }

  // C/D layout: col = lane&15, row = (lane>>4)*4 + reg
  const int ccol = lane & 15;
  const int cr0 = (lane >> 4) * 4;
#pragma unroll
  for (int i = 0; i < 4; ++i) {
#pragma unroll
    for (int r = 0; r < 4; ++r) {
      int row = rb + wr + i * 16 + cr0 + r;
      if (row < Me) {
        if (FIRST) {
          unsigned short* hrow = Hout + (size_t)(off + row) * N;
#pragma unroll
          for (int j = 0; j < 4; ++j) {
            float v = acc[i][j][r];
            float s = v / (1.0f + __expf(-v));   // silu
            hrow[cb + wc + j * 16 + ccol] = f2bf(s);
          }
        } else {
          int tok = perm[off + row];
          float* orow = Out + (size_t)tok * N;
#pragma unroll
          for (int j = 0; j < 4; ++j)
            orow[cb + wc + j * 16 + ccol] = acc[i][j][r];
        }
      }
    }
  }
}

extern "C" void kernel_launch(void* const* d_in, const int* in_sizes, int n_in,
                              void* d_out, int out_size, void* d_ws, size_t ws_size,
                              hipStream_t stream) {
  const float* x      = (const float*)d_in[0];   // [T, D] fp32
  const float* logits = (const float*)d_in[1];   // [T, E] fp32
  const float* w1     = (const float*)d_in[2];   // [E, F, D] fp32
  const float* w2     = (const float*)d_in[3];   // [E, D, F] fp32
  float* out = (float*)d_out;                    // [T, D] fp32

  char* ws = (char*)d_ws;
  int* counts  = (int*)(ws + 0);
  int* offsets = (int*)(ws + 64);
  int* cursors = (int*)(ws + 128);
  int* assign  = (int*)(ws + 4096);
  int* perm    = (int*)(ws + 4096 + T_TOKENS * 4);
  size_t p = 4096 + (size_t)2 * T_TOKENS * 4;
  p = (p + 255) & ~(size_t)255;
  unsigned short* Xg  = (unsigned short*)(ws + p); p += (size_t)T_TOKENS * DDIM * 2;
  unsigned short* W1b = (unsigned short*)(ws + p); p += (size_t)NEXP * FDIM * DDIM * 2;
  unsigned short* W2b = (unsigned short*)(ws + p); p += (size_t)NEXP * DDIM * FDIM * 2;
  unsigned short* Hb  = (unsigned short*)(ws + p); p += (size_t)T_TOKENS * FDIM * 2;
  if (ws_size < p) return;  // ~369 MB required

  hipMemsetAsync(ws, 0, 4096, stream);  // counts + cursors
  k_assign<<<T_TOKENS / 256, 256, 0, stream>>>(logits, assign, counts);
  k_scan<<<1, 64, 0, stream>>>(counts, offsets);
  k_place<<<T_TOKENS / 256, 256, 0, stream>>>(assign, offsets, cursors, perm);
  k_gather_x<<<(T_TOKENS * (DDIM / 4)) / 256, 256, 0, stream>>>(x, perm, Xg);
  int n4 = NEXP * FDIM * (DDIM / 4);
  k_cast<<<n4 / 256, 256, 0, stream>>>(w1, W1b, n4);
  k_cast<<<n4 / 256, 256, 0, stream>>>(w2, W2b, n4);
  k_gemm<true><<<dim3(T_TOKENS / 128, FDIM / 128, NEXP), 256, 0, stream>>>(
      Xg, W1b, Hb, nullptr, offsets, counts, perm);
  k_gemm<false><<<dim3(T_TOKENS / 128, DDIM / 128, NEXP), 256, 0, stream>>>(
      Hb, W2b, nullptr, out, offsets, counts, perm);
}

// Round 2
// 1184.721 us; speedup vs baseline: 1.7937x; 1.7937x over previous
//
#include <hip/hip_runtime.h>
#include <stdint.h>

#define T_TOKENS 8192
#define DDIM 2048
#define FDIM 4096
#define NEXP 8
#define MAXTILES 72

typedef __attribute__((ext_vector_type(8))) short bf16x8;
typedef __attribute__((ext_vector_type(4))) float f32x4;

// round-to-nearest-even fp32 -> bf16 (finite inputs)
__device__ __forceinline__ unsigned short f2bf(float f) {
  unsigned int u = __float_as_uint(f);
  unsigned int r = (u + 0x7FFFu + ((u >> 16) & 1u)) >> 16;
  return (unsigned short)r;
}

__global__ void k_assign(const float* __restrict__ logits,
                         int* __restrict__ assign,
                         int* __restrict__ counts) {
  int t = blockIdx.x * blockDim.x + threadIdx.x;
  if (t >= T_TOKENS) return;
  const float* l = logits + (size_t)t * NEXP;
  float bv = l[0]; int be = 0;
#pragma unroll
  for (int e = 1; e < NEXP; ++e) {
    float v = l[e];
    if (v > bv) { bv = v; be = e; }   // strict > : first-max tiebreak like jnp.argmax
  }
  assign[t] = be;
  atomicAdd(&counts[be], 1);
}

// offsets + tile table: (expert, row-tile) pairs, nt <= 64 + 7 = 71 always
__global__ void k_scan(const int* __restrict__ counts,
                       int* __restrict__ offsets,
                       int* __restrict__ tile_e,
                       int* __restrict__ tile_rb,
                       int* __restrict__ ntiles) {
  if (threadIdx.x == 0) {
    int acc = 0, nt = 0;
    for (int e = 0; e < NEXP; ++e) {
      offsets[e] = acc;
      int c = counts[e];
      acc += c;
      int t = (c + 127) >> 7;
      for (int i = 0; i < t; ++i) { tile_e[nt] = e; tile_rb[nt] = i; ++nt; }
    }
    ntiles[0] = nt;
  }
}

__global__ void k_place(const int* __restrict__ assign,
                        const int* __restrict__ offsets,
                        int* __restrict__ cursors,
                        int* __restrict__ perm) {
  int t = blockIdx.x * blockDim.x + threadIdx.x;
  if (t >= T_TOKENS) return;
  int e = assign[t];
  int pos = atomicAdd(&cursors[e], 1);
  perm[offsets[e] + pos] = t;
}

// gather tokens into bucket order, cast fp32 -> bf16
__global__ void k_gather_x(const float* __restrict__ x,
                           const int* __restrict__ perm,
                           unsigned short* __restrict__ xg) {
  int idx = blockIdx.x * blockDim.x + threadIdx.x;   // over T*D/4
  int slot = idx / (DDIM / 4);
  int c4 = idx - slot * (DDIM / 4);
  int tok = perm[slot];
  float4 v = ((const float4*)(x + (size_t)tok * DDIM))[c4];
  ushort4 o;
  o.x = f2bf(v.x); o.y = f2bf(v.y); o.z = f2bf(v.z); o.w = f2bf(v.w);
  ((ushort4*)(xg + (size_t)slot * DDIM))[c4] = o;
}

__global__ void k_cast(const float* __restrict__ src,
                       unsigned short* __restrict__ dst, int n4) {
  int i = blockIdx.x * blockDim.x + threadIdx.x;
  if (i >= n4) return;
  float4 v = ((const float4*)src)[i];
  ushort4 o;
  o.x = f2bf(v.x); o.y = f2bf(v.y); o.z = f2bf(v.z); o.w = f2bf(v.w);
  ((ushort4*)dst)[i] = o;
}

__device__ __forceinline__ void glds(const unsigned short* g, unsigned short* l) {
  __builtin_amdgcn_global_load_lds(
      (const __attribute__((address_space(1))) void*)g,
      (__attribute__((address_space(3))) void*)l, 16, 0, 0);
}

// Grouped GEMM: 128x128 tile, BK=32, mfma_f32_16x16x32_bf16, 4 waves x (64x64).
// 3-buffer LDS pipeline, prefetch distance 2, single raw barrier per k-step with
// fine-grained vmcnt(4) so prefetch loads stay in flight across the barrier.
// Per wave per iteration: exactly 4 global_load_lds (2 A + 2 B chunks).
template<bool FIRST>
__launch_bounds__(256)
__global__ void k_gemm(const unsigned short* __restrict__ Ap,
                       const unsigned short* __restrict__ Bw,
                       unsigned short* __restrict__ Hout,
                       float* __restrict__ Out,
                       const int* __restrict__ offsets,
                       const int* __restrict__ counts,
                       const int* __restrict__ perm,
                       const int* __restrict__ tile_e,
                       const int* __restrict__ tile_rb,
                       const int* __restrict__ ntiles) {
  constexpr int K = FIRST ? DDIM : FDIM;
  constexpr int N = FIRST ? FDIM : DDIM;
  constexpr int NSTEP = K / 32;
  const int ty = blockIdx.y;
  if (ty >= ntiles[0]) return;
  const int e  = tile_e[ty];
  const int rb = tile_rb[ty] << 7;
  const int off = offsets[e];
  const int Me = counts[e];
  const int cb = blockIdx.x << 7;

  __shared__ unsigned short At[3][128 * 32];   // 3 x 8 KB
  __shared__ unsigned short Bt[3][128 * 32];   // 3 x 8 KB  (48 KB total)

  const int tid = threadIdx.x;
  const int wave = tid >> 6;
  const int lane = tid & 63;
  const int wr = (wave & 1) << 6;
  const int wc = (wave >> 1) << 6;

  // staging: tile (128 rows x 32 k) = 8 chunks of 16 rows; wave w owns chunks 2w,2w+1
  // within a chunk: lane l -> row = l>>2, k-seg = (l&3)*8 shorts  (16B per lane)
  const int crow = lane >> 2;
  const int ckoff = (lane & 3) * 8;

  const unsigned short* gA[2];
  const unsigned short* gB[2];
#pragma unroll
  for (int c = 0; c < 2; ++c) {
    int row = wave * 32 + c * 16 + crow;
    int ar = rb + row; if (ar >= Me) ar = Me - 1;   // clamp ragged M (unused rows masked in epilogue)
    gA[c] = Ap + (size_t)(off + ar) * K + ckoff;
    gB[c] = Bw + (size_t)e * N * K + (size_t)(cb + row) * K + ckoff;
  }
  const int ldsoff = wave * 1024;   // shorts; +c*512 per chunk

  // prologue: tiles 0 and 1 (oldest-first issue order matters for vmcnt)
#pragma unroll
  for (int s = 0; s < 2; ++s) {
#pragma unroll
    for (int c = 0; c < 2; ++c) {
      glds(gA[c] + s * 32, &At[s][ldsoff + c * 512]);
      glds(gB[c] + s * 32, &Bt[s][ldsoff + c * 512]);
    }
  }

  f32x4 acc[4][4] = {};
  int s_cur = 0, s_pre = 2;
  for (int ks = 0; ks < NSTEP; ++ks) {
    // wait ONLY the 4 oldest loads (tile ks); tile ks+1 stays in flight.
    asm volatile("s_waitcnt vmcnt(4) lgkmcnt(0)\n\ts_barrier" ::: "memory");

    // prefetch tile ks+2 (dummy wrap at the tail keeps the vmcnt invariant uniform)
    int ka = ks + 2; if (ka >= NSTEP) ka -= NSTEP;
    const int kadd = ka * 32;
#pragma unroll
    for (int c = 0; c < 2; ++c) {
      glds(gA[c] + kadd, &At[s_pre][ldsoff + c * 512]);
      glds(gB[c] + kadd, &Bt[s_pre][ldsoff + c * 512]);
    }

    bf16x8 af[4], bfr[4];
#pragma unroll
    for (int i = 0; i < 4; ++i) {
      // A-operand layout: m = lane&15, k = (lane>>4)*8 + j  -> contiguous 16B
      af[i]  = *(const bf16x8*)&At[s_cur][(wr + i * 16 + (lane & 15)) * 32 + (lane >> 4) * 8];
      bfr[i] = *(const bf16x8*)&Bt[s_cur][(wc + i * 16 + (lane & 15)) * 32 + (lane >> 4) * 8];
    }
#pragma unroll
    for (int i = 0; i < 4; ++i)
#pragma unroll
      for (int j = 0; j < 4; ++j)
        acc[i][j] = __builtin_amdgcn_mfma_f32_16x16x32_bf16(af[i], bfr[j], acc[i][j], 0, 0, 0);

    s_cur = (s_cur == 2) ? 0 : s_cur + 1;
    s_pre = (s_pre == 2) ? 0 : s_pre + 1;
  }

  // C/D layout: col = lane&15, row = (lane>>4)*4 + reg
  const int ccol = lane & 15;
  const int cr0 = (lane >> 4) * 4;
#pragma unroll
  for (int i = 0; i < 4; ++i) {
#pragma unroll
    for (int r = 0; r < 4; ++r) {
      int row = rb + wr + i * 16 + cr0 + r;
      if (row < Me) {
        if (FIRST) {
          unsigned short* hrow = Hout + (size_t)(off + row) * N;
#pragma unroll
          for (int j = 0; j < 4; ++j) {
            float v = acc[i][j][r];
            float s = v / (1.0f + __expf(-v));   // silu
            hrow[cb + wc + j * 16 + ccol] = f2bf(s);
          }
        } else {
          int tok = perm[off + row];
          float* orow = Out + (size_t)tok * N;
#pragma unroll
          for (int j = 0; j < 4; ++j)
            orow[cb + wc + j * 16 + ccol] = acc[i][j][r];
        }
      }
    }
  }
}

extern "C" void kernel_launch(void* const* d_in, const int* in_sizes, int n_in,
                              void* d_out, int out_size, void* d_ws, size_t ws_size,
                              hipStream_t stream) {
  const float* x      = (const float*)d_in[0];   // [T, D] fp32
  const float* logits = (const float*)d_in[1];   // [T, E] fp32
  const float* w1     = (const float*)d_in[2];   // [E, F, D] fp32
  const float* w2     = (const float*)d_in[3];   // [E, D, F] fp32
  float* out = (float*)d_out;                    // [T, D] fp32

  char* ws = (char*)d_ws;
  int* counts  = (int*)(ws + 0);
  int* offsets = (int*)(ws + 64);
  int* cursors = (int*)(ws + 128);
  int* tile_e  = (int*)(ws + 256);    // 72 ints
  int* tile_rb = (int*)(ws + 1024);   // 72 ints
  int* ntiles  = (int*)(ws + 2048);
  int* assign  = (int*)(ws + 4096);
  int* perm    = (int*)(ws + 4096 + T_TOKENS * 4);
  size_t p = 4096 + (size_t)2 * T_TOKENS * 4;
  p = (p + 255) & ~(size_t)255;
  unsigned short* Xg  = (unsigned short*)(ws + p); p += (size_t)T_TOKENS * DDIM * 2;
  unsigned short* W1b = (unsigned short*)(ws + p); p += (size_t)NEXP * FDIM * DDIM * 2;
  unsigned short* W2b = (unsigned short*)(ws + p); p += (size_t)NEXP * DDIM * FDIM * 2;
  unsigned short* Hb  = (unsigned short*)(ws + p); p += (size_t)T_TOKENS * FDIM * 2;
  if (ws_size < p) return;  // ~369 MB required

  hipMemsetAsync(ws, 0, 4096, stream);  // counts + cursors + tables
  k_assign<<<T_TOKENS / 256, 256, 0, stream>>>(logits, assign, counts);
  k_scan<<<1, 64, 0, stream>>>(counts, offsets, tile_e, tile_rb, ntiles);
  k_place<<<T_TOKENS / 256, 256, 0, stream>>>(assign, offsets, cursors, perm);
  k_gather_x<<<(T_TOKENS * (DDIM / 4)) / 256, 256, 0, stream>>>(x, perm, Xg);
  int n4 = NEXP * FDIM * (DDIM / 4);
  k_cast<<<n4 / 256, 256, 0, stream>>>(w1, W1b, n4);
  k_cast<<<n4 / 256, 256, 0, stream>>>(w2, W2b, n4);
  k_gemm<true><<<dim3(FDIM / 128, MAXTILES), 256, 0, stream>>>(
      Xg, W1b, Hb, nullptr, offsets, counts, perm, tile_e, tile_rb, ntiles);
  k_gemm<false><<<dim3(DDIM / 128, MAXTILES), 256, 0, stream>>>(
      Hb, W2b, nullptr, out, offsets, counts, perm, tile_e, tile_rb, ntiles);
}